// Round 8
// baseline (1011.678 us; speedup 1.0000x reference)
//
#include <hip/hip_runtime.h>
#include <hip/hip_bf16.h>
#include <stdint.h>

#define SEQ   2048
#define DIN   5
#define HID   64
#define DTC   0.1f

typedef __attribute__((ext_vector_type(8))) __bf16  bf16x8;
typedef __attribute__((ext_vector_type(8))) short   short8;
typedef __attribute__((ext_vector_type(4))) float   f32x4;
typedef __attribute__((ext_vector_type(4))) int     i32x4;
typedef __attribute__((ext_vector_type(2))) int     i32x2;
typedef unsigned long long u64;

__device__ __forceinline__ unsigned short f2bf(float f) {
    unsigned int u = __builtin_bit_cast(unsigned int, f);
    return (unsigned short)((u + 0x7FFFu + ((u >> 16) & 1u)) >> 16);  // RNE
}

__device__ __forceinline__ float fast_tanh(float x) {
    float e = __expf(2.0f * x);                       // saturates correctly at +-1
    return 1.0f - 2.0f * __builtin_amdgcn_rcpf(e + 1.0f);
}

__device__ __forceinline__ unsigned int cvt_pk_bf16(float lo, float hi) {
    unsigned int r;
    asm("v_cvt_pk_bf16_f32 %0, %1, %2" : "=v"(r) : "v"(lo), "v"(hi));
    return r;
}

// ONE wave per block owns a full 16-batch-col x 64-hidden tile:
//   4 M-tiles (rows 16m..16m+15) x 2 K-tiles, B-fragments shared across M.
// tanh exchange is INTRA-WAVE via a single 2KB fragment-linear LDS buffer:
// no __syncthreads in the loop; per-wave DS ordering + explicit lgkmcnt(0)
// after the writes. Reads come first in each step (single buffer correct).
// MFMAs issued in 3 m-unrolled passes so in-order issue never stalls on the
// accumulator dependency (distance-4 between dependent MFMAs).
__global__ __launch_bounds__(64) void ltc_kernel(
    const float* __restrict__ x,
    const float* __restrict__ tau,
    const float* __restrict__ Wih,
    const float* __restrict__ bih,
    const float* __restrict__ Whh,
    const float* __restrict__ bhh,
    const float* __restrict__ outw,
    const float* __restrict__ outb,
    float* __restrict__ out)
{
    const int lane = threadIdx.x & 63;
    const int lg   = lane >> 4;
    const int ln   = lane & 15;
    const int b0   = blockIdx.x * 16;

    __shared__ __align__(16) unsigned short sbuf[1024];  // k-tile0: bytes 0..1023, k-tile1: 1024..2047

    // per-lane constants: C/D rows 16m+4lg+r, A rows 16m+ln  (verified layouts)
    float a[4][4], ow[4][4];
#pragma unroll
    for (int m = 0; m < 4; ++m)
#pragma unroll
        for (int r = 0; r < 4; ++r) {
            const int j = 16 * m + 4 * lg + r;
            a[m][r]  = 1.0f - DTC / fabsf(tau[j]);
            ow[m][r] = outw[j];
        }

    bf16x8 Ahh[4][2], Aih[4];
#pragma unroll
    for (int m = 0; m < 4; ++m) {
        const int row = 16 * m + ln;
#pragma unroll
        for (int kt = 0; kt < 2; ++kt) {
            short8 s;
#pragma unroll
            for (int q = 0; q < 8; ++q)
                s[q] = (short)f2bf(DTC * Whh[row * HID + kt * 32 + lg * 8 + q]);
            Ahh[m][kt] = __builtin_bit_cast(bf16x8, s);
        }
        short8 sx = {0,0,0,0,0,0,0,0};
        if (lg == 0) {
#pragma unroll
            for (int d = 0; d < DIN; ++d) sx[d] = (short)f2bf(DTC * Wih[row * DIN + d]);
            sx[5] = (short)f2bf(DTC * (bih[row] + bhh[row]));
        }
        Aih[m] = __builtin_bit_cast(bf16x8, sx);
    }

    // write slots (fragment-linear, r2-r7-verified formula), one per M-tile
    int wbyte[4];
#pragma unroll
    for (int m = 0; m < 4; ++m) {
        const int jb = 16 * m + 4 * lg;
        wbyte[m] = ((jb >= 32) ? 1024 : 0) + (((jb & 31) >> 3) * 256)
                 + ln * 16 + (((jb >> 2) & 1) * 8);
    }

    // zero-init buffer (t=0 reads tanh(h0)=0); same wave -> in-order vs reads
#pragma unroll
    for (int i = 0; i < 4; ++i) ((u64*)sbuf)[lane * 4 + i] = 0ULL;

    const char* const rdp0 = (const char*)sbuf + lane * 16;
    const char* const rdp1 = (const char*)sbuf + 1024 + lane * 16;

    // depth-2 x prefetch (each lane loads its own batch column b0+ln)
    const float* xb = x + (size_t)(b0 + ln) * (SEQ * DIN);
    float ex[DIN], ox[DIN];
#pragma unroll
    for (int d = 0; d < DIN; ++d) { ex[d] = xb[d]; ox[d] = xb[DIN + d]; }
    const float* xnext = xb + 2 * DIN;   // -> x[t+2]

    f32x4 h[4];
#pragma unroll
    for (int m = 0; m < 4; ++m) { h[m][0]=0.f; h[m][1]=0.f; h[m][2]=0.f; h[m][3]=0.f; }

#define STEP(PX, PF, XADD)                                                          \
    {                                                                               \
        /* reads FIRST (single buffer): B-fragments of tanh(h_{t-1}) */             \
        i32x4 r0 = *(const i32x4*)rdp0;                                             \
        i32x4 r1 = *(const i32x4*)rdp1;                                             \
        i32x4 bx;                                                                   \
        bx[0] = (int)cvt_pk_bf16(PX[0], PX[1]);                                     \
        bx[1] = (int)cvt_pk_bf16(PX[2], PX[3]);                                     \
        bx[2] = (int)cvt_pk_bf16(PX[4], 1.0f);                                      \
        bx[3] = 0;                                                                  \
        if (PF) {                                                                   \
            _Pragma("unroll")                                                       \
            for (int d = 0; d < DIN; ++d) PX[d] = xnext[(XADD) + d];                \
        }                                                                           \
        f32x4 c[4];                                                                 \
        _Pragma("unroll")                                                           \
        for (int m = 0; m < 4; ++m) {                                               \
            c[m][0] = a[m][0]*h[m][0]; c[m][1] = a[m][1]*h[m][1];                   \
            c[m][2] = a[m][2]*h[m][2]; c[m][3] = a[m][3]*h[m][3];                   \
        }                                                                           \
        _Pragma("unroll")                                                           \
        for (int m = 0; m < 4; ++m)                                                 \
            c[m] = __builtin_amdgcn_mfma_f32_16x16x32_bf16(Aih[m], __builtin_bit_cast(bf16x8, bx), c[m], 0, 0, 0); \
        _Pragma("unroll")                                                           \
        for (int m = 0; m < 4; ++m)                                                 \
            c[m] = __builtin_amdgcn_mfma_f32_16x16x32_bf16(Ahh[m][0], __builtin_bit_cast(bf16x8, r0), c[m], 0, 0, 0); \
        _Pragma("unroll")                                                           \
        for (int m = 0; m < 4; ++m)                                                 \
            c[m] = __builtin_amdgcn_mfma_f32_16x16x32_bf16(Ahh[m][1], __builtin_bit_cast(bf16x8, r1), c[m], 0, 0, 0); \
        _Pragma("unroll")                                                           \
        for (int m = 0; m < 4; ++m) {                                               \
            h[m] = c[m];                                                            \
            float t0 = fast_tanh(c[m][0]), t1 = fast_tanh(c[m][1]);                 \
            float t2 = fast_tanh(c[m][2]), t3 = fast_tanh(c[m][3]);                 \
            i32x2 w; w[0] = (int)cvt_pk_bf16(t0, t1); w[1] = (int)cvt_pk_bf16(t2, t3); \
            *(i32x2*)((char*)sbuf + wbyte[m]) = w;                                  \
        }                                                                           \
        /* drain writes before next step's reads (same wave, no barrier) */         \
        asm volatile("s_waitcnt lgkmcnt(0)" ::: "memory");                          \
    }

    for (int t = 0; t < SEQ - 2; t += 2) {
        STEP(ex, true, 0)
        STEP(ox, true, DIN)
        xnext += 2 * DIN;
    }
    STEP(ex, false, 0)   // t = SEQ-2
    STEP(ox, false, 0)   // t = SEQ-1
#undef STEP

    // epilogue: out[b] = tanh(h_final) . out_w + out_b ; reduce 4 lane-groups
    float part = 0.0f;
#pragma unroll
    for (int m = 0; m < 4; ++m)
#pragma unroll
        for (int r = 0; r < 4; ++r)
            part += fast_tanh(h[m][r]) * ow[m][r];
    part += __shfl_down(part, 32);
    part += __shfl_down(part, 16);
    if (lane < 16) out[b0 + ln] = part + outb[0];
}

extern "C" void kernel_launch(void* const* d_in, const int* in_sizes, int n_in,
                              void* d_out, int out_size, void* d_ws, size_t ws_size,
                              hipStream_t stream) {
    const float* x    = (const float*)d_in[0];
    const float* tau  = (const float*)d_in[1];
    const float* Wih  = (const float*)d_in[2];
    const float* bih  = (const float*)d_in[3];
    const float* Whh  = (const float*)d_in[4];
    const float* bhh  = (const float*)d_in[5];
    const float* outw = (const float*)d_in[6];
    const float* outb = (const float*)d_in[7];
    float* out = (float*)d_out;

    const int batch = in_sizes[0] / (SEQ * DIN);   // 4096
    ltc_kernel<<<batch / 16, 64, 0, stream>>>(x, tau, Wih, bih, Whh, bhh, outw, outb, out);
}

// Round 9
// 531.745 us; speedup vs baseline: 1.9026x; 1.9026x over previous
//
#include <hip/hip_runtime.h>
#include <hip/hip_bf16.h>
#include <stdint.h>

#define SEQ   2048
#define DIN   5
#define HID   64
#define DTC   0.1f
#define BTILE 16
#define NWAVE 4

typedef __attribute__((ext_vector_type(8))) __bf16  bf16x8;
typedef __attribute__((ext_vector_type(8))) short   short8;
typedef __attribute__((ext_vector_type(4))) float   f32x4;
typedef __attribute__((ext_vector_type(4))) int     i32x4;
typedef __attribute__((ext_vector_type(2))) int     i32x2;
typedef unsigned long long u64;

__device__ __forceinline__ unsigned short f2bf(float f) {
    unsigned int u = __builtin_bit_cast(unsigned int, f);
    return (unsigned short)((u + 0x7FFFu + ((u >> 16) & 1u)) >> 16);  // RNE
}

__device__ __forceinline__ float fast_tanh(float x) {
    float e = __expf(2.0f * x);                       // saturates correctly at +-1
    return 1.0f - 2.0f * __builtin_amdgcn_rcpf(e + 1.0f);
}

__device__ __forceinline__ unsigned int cvt_pk_bf16(float lo, float hi) {
    unsigned int r;
    asm("v_cvt_pk_bf16_f32 %0, %1, %2" : "=v"(r) : "v"(lo), "v"(hi));
    return r;
}

// r3 structure (256 blocks x 4 waves; wave w owns hidden rows [16w,16w+16);
// double-buffered fragment-linear LDS exchange, conflict-free reads) with:
//  (1) SOFT BARRIER: s_waitcnt lgkmcnt(0) + s_barrier — no vmcnt(0) drain.
//      Cross-wave traffic is LDS-only, so draining VMEM at the barrier
//      (what __syncthreads does) is unnecessary; it was stalling every
//      step on the in-flight x prefetch.
//  (2) x loaded as float4 groups, 8 steps (40 floats) per superstep into
//      ping-ponged register sets; all indexing compile-time.
__global__ __launch_bounds__(256) void ltc_kernel(
    const float* __restrict__ x,
    const float* __restrict__ tau,
    const float* __restrict__ Wih,
    const float* __restrict__ bih,
    const float* __restrict__ Whh,
    const float* __restrict__ bhh,
    const float* __restrict__ outw,
    const float* __restrict__ outb,
    float* __restrict__ out)
{
    const int tid  = threadIdx.x;
    const int wave = tid >> 6;
    const int lane = tid & 63;
    const int lg   = lane >> 4;
    const int ln   = lane & 15;
    const int b0   = blockIdx.x * BTILE;

    __shared__ __align__(16) unsigned short sbuf[2][1024];  // 2 x 2KB fragment buffers
    __shared__ float redbuf[NWAVE][4][BTILE];

    const int jbase = 16 * wave + 4 * lg;   // first C/D row (hidden idx) of this lane
    const int arow  = 16 * wave + ln;       // A-fragment row (hidden idx)

    float a[4], ow[4];
#pragma unroll
    for (int r = 0; r < 4; ++r) {
        a[r]  = 1.0f - DTC / fabsf(tau[jbase + r]);
        ow[r] = outw[jbase + r];
    }

    // A fragments: lane l holds A[l&15][(l>>4)*8 + q]  (verified r2/r3/r7)
    short8 s0 = {0,0,0,0,0,0,0,0}, s1 = {0,0,0,0,0,0,0,0}, s2 = {0,0,0,0,0,0,0,0};
#pragma unroll
    for (int q = 0; q < 8; ++q) {
        s0[q] = (short)f2bf(DTC * Whh[arow * HID + lg * 8 + q]);
        s1[q] = (short)f2bf(DTC * Whh[arow * HID + 32 + lg * 8 + q]);
    }
    if (lg == 0) {
#pragma unroll
        for (int d = 0; d < DIN; ++d) s2[d] = (short)f2bf(DTC * Wih[arow * DIN + d]);
        s2[5] = (short)f2bf(DTC * (bih[arow] + bhh[arow]));
    }
    const bf16x8 Ahh0 = __builtin_bit_cast(bf16x8, s0);
    const bf16x8 Ahh1 = __builtin_bit_cast(bf16x8, s1);
    const bf16x8 Aix  = __builtin_bit_cast(bf16x8, s2);

    // write slot (fragment-linear): rows jbase..jbase+3, col ln
    const int wbyte = ((jbase >= 32) ? 1024 : 0) + (((jbase & 31) >> 3) * 256)
                    + ln * 16 + (((jbase >> 2) & 1) * 8);
    char* const wp0 = (char*)sbuf[0] + wbyte;
    char* const wp1 = (char*)sbuf[1] + wbyte;
    const char* const rp0 = (const char*)sbuf[0] + lane * 16;
    const char* const rp1 = (const char*)sbuf[1] + lane * 16;

    // zero parity-1 buffer (read at t=0: tanh(h0)=0)
    ((u64*)sbuf[1])[tid] = 0ULL;

    // x: per-lane row, loaded in 8-step groups (40 floats = 10 float4, aligned:
    // offset 8t*5*4B = 160t bytes, 16B-aligned)
    const float* xb = x + (size_t)(b0 + ln) * (SEQ * DIN);
    f32x4 bufA[10], bufB[10];
#pragma unroll
    for (int i = 0; i < 10; ++i) bufA[i] = *(const f32x4*)(xb + 4 * i);  // steps 0..7

    f32x4 h = {0.f, 0.f, 0.f, 0.f};

    // soft barrier: order LDS writes cross-wave; do NOT drain vmcnt
#define SBAR() asm volatile("s_waitcnt lgkmcnt(0)\n\ts_barrier" ::: "memory")

#define BODY(PAR, X0, X1, X2, X3, X4)                                              \
    {                                                                              \
        const char* rb = (PAR) ? rp0 : rp1;        /* read parity = !PAR */        \
        i32x4 r0 = *(const i32x4*)(rb);                                            \
        i32x4 r1 = *(const i32x4*)(rb + 1024);                                     \
        i32x4 bx;                                                                  \
        bx[0] = (int)cvt_pk_bf16(X0, X1);                                          \
        bx[1] = (int)cvt_pk_bf16(X2, X3);                                          \
        bx[2] = (int)cvt_pk_bf16(X4, 1.0f);                                        \
        bx[3] = 0;                                                                 \
        f32x4 c;                                                                   \
        c[0] = a[0]*h[0]; c[1] = a[1]*h[1]; c[2] = a[2]*h[2]; c[3] = a[3]*h[3];    \
        c = __builtin_amdgcn_mfma_f32_16x16x32_bf16(Aix,  __builtin_bit_cast(bf16x8, bx), c, 0, 0, 0); \
        c = __builtin_amdgcn_mfma_f32_16x16x32_bf16(Ahh0, __builtin_bit_cast(bf16x8, r0), c, 0, 0, 0); \
        c = __builtin_amdgcn_mfma_f32_16x16x32_bf16(Ahh1, __builtin_bit_cast(bf16x8, r1), c, 0, 0, 0); \
        h = c;                                                                     \
        float t0 = fast_tanh(c[0]), t1 = fast_tanh(c[1]);                          \
        float t2 = fast_tanh(c[2]), t3 = fast_tanh(c[3]);                          \
        i32x2 w; w[0] = (int)cvt_pk_bf16(t0, t1); w[1] = (int)cvt_pk_bf16(t2, t3); \
        *(i32x2*)((PAR) ? wp1 : wp0) = w;                                          \
    }

    // 8 steps per superstep; x-floats for step s are elements [5s..5s+4]
#define SUPER(BUF, DO_LOAD, LBUF, LOFF)                                            \
    SBAR();                                                                        \
    if (DO_LOAD) {                                                                 \
        _Pragma("unroll")                                                          \
        for (int i = 0; i < 10; ++i) LBUF[i] = *(const f32x4*)(xb + (LOFF) + 4*i); \
    }                                                                              \
    BODY(0, BUF[0][0], BUF[0][1], BUF[0][2], BUF[0][3], BUF[1][0])                 \
    SBAR(); BODY(1, BUF[1][1], BUF[1][2], BUF[1][3], BUF[2][0], BUF[2][1])         \
    SBAR(); BODY(0, BUF[2][2], BUF[2][3], BUF[3][0], BUF[3][1], BUF[3][2])         \
    SBAR(); BODY(1, BUF[3][3], BUF[4][0], BUF[4][1], BUF[4][2], BUF[4][3])         \
    SBAR(); BODY(0, BUF[5][0], BUF[5][1], BUF[5][2], BUF[5][3], BUF[6][0])         \
    SBAR(); BODY(1, BUF[6][1], BUF[6][2], BUF[6][3], BUF[7][0], BUF[7][1])         \
    SBAR(); BODY(0, BUF[7][2], BUF[7][3], BUF[8][0], BUF[8][1], BUF[8][2])         \
    SBAR(); BODY(1, BUF[8][3], BUF[9][0], BUF[9][1], BUF[9][2], BUF[9][3])

    for (int it = 0; it < SEQ / 16; ++it) {
        SUPER(bufA, true,            bufB, (it * 16 + 8)  * DIN)   // steps 16it..+7
        SUPER(bufB, it != SEQ/16 - 1, bufA, (it * 16 + 16) * DIN)  // steps 16it+8..+15
    }
#undef SUPER
#undef BODY
#undef SBAR

    // epilogue: out[b] = tanh(h_final) . out_w + out_b
    float part = fast_tanh(h[0]) * ow[0] + fast_tanh(h[1]) * ow[1]
               + fast_tanh(h[2]) * ow[2] + fast_tanh(h[3]) * ow[3];
    redbuf[wave][lg][ln] = part;
    __syncthreads();
    if (tid < BTILE) {
        float s = outb[0];
#pragma unroll
        for (int w = 0; w < NWAVE; ++w)
#pragma unroll
            for (int g = 0; g < 4; ++g) s += redbuf[w][g][tid];
        out[b0 + tid] = s;
    }
}

extern "C" void kernel_launch(void* const* d_in, const int* in_sizes, int n_in,
                              void* d_out, int out_size, void* d_ws, size_t ws_size,
                              hipStream_t stream) {
    const float* x    = (const float*)d_in[0];
    const float* tau  = (const float*)d_in[1];
    const float* Wih  = (const float*)d_in[2];
    const float* bih  = (const float*)d_in[3];
    const float* Whh  = (const float*)d_in[4];
    const float* bhh  = (const float*)d_in[5];
    const float* outw = (const float*)d_in[6];
    const float* outb = (const float*)d_in[7];
    float* out = (float*)d_out;

    const int batch = in_sizes[0] / (SEQ * DIN);   // 4096
    ltc_kernel<<<batch / BTILE, NWAVE * 64, 0, stream>>>(x, tau, Wih, bih, Whh, bhh, outw, outb, out);
}